// Round 22
// baseline (203.079 us; speedup 1.0000x reference)
//
#include <hip/hip_runtime.h>
#include <hip/hip_bf16.h>
#include <stdint.h>

#define NE    64
#define DIN   512
#define DOUT  512
#define TTOK  131072
#define BM    256
#define BN    256
#define BK    32
#define NKT   (DIN / BK)              // 16 K-tiles
#define TILES_TOTAL (TTOK / BM + NE)  // 576 (grid bound)
#define NXCD  8

typedef __bf16 bf16x8_t __attribute__((ext_vector_type(8)));
typedef float  f32x4_t  __attribute__((ext_vector_type(4)));

// LDS 144 KB, ring-of-3 on BOTH operands (1 block/CU is register-forced:
// 64 AGPR acc + ~46 arch; 1024 thr):
//   A ring: 3 x 32 KB (256 rows x 128B fp32 = 32 k; preswizzled src, (row&7))
//   B ring: 3 x 16 KB (128 LDS rows x 128B bf16; row lr = dout {lr, lr+128})
// Visibility rule (R19): each wave drains its OWN t+1 DMAs (counted WAITV(3))
// BEFORE the single barrier; consumers read after it.
#define ABUF(i) ((i) * 32768)
#define BBUF(i) (98304 + (i) * 16384)
#define LDS_BYTES 147456

#define WAITV(n) asm volatile("s_waitcnt vmcnt(" #n ")" ::: "memory")
#define SB() __builtin_amdgcn_sched_barrier(0)
#define BAR() __builtin_amdgcn_s_barrier()

// ws layout: ws[0] = ntiles; tile table (int4) at ws+4; bf16 weight at +32KB
#define WBF_OFF 32768

__global__ void setup_tiles(const int* __restrict__ cnt, int* __restrict__ ws) {
    int e = threadIdx.x;
    if (e >= NE) return;
    int off = 0, tbase = 0;
    for (int i = 0; i < e; ++i) {
        int c = cnt[i];
        off += c;
        tbase += (c + (BM - 1)) / BM;
    }
    int c = cnt[e];
    int nt = (c + (BM - 1)) / BM;
    int* tbl = ws + 4;
    for (int t = 0; t < nt; ++t) {
        int idx = tbase + t;
        tbl[4 * idx + 0] = e;
        tbl[4 * idx + 1] = off + t * BM;
        tbl[4 * idx + 2] = off + c;
        tbl[4 * idx + 3] = 0;
    }
    if (e == NE - 1) ws[0] = tbase + nt;
}

// weight fp32 -> bf16, streaming
__global__ __launch_bounds__(256) void wcvt(const float* __restrict__ w,
                                            __bf16* __restrict__ wbf) {
    const size_t stride = (size_t)gridDim.x * 256;
    size_t i = (size_t)blockIdx.x * 256 + threadIdx.x;
    const size_t n8 = (size_t)NE * DOUT * DIN / 8;
    for (; i < n8; i += stride) {
        f32x4_t a = *(const f32x4_t*)(w + i * 8);
        f32x4_t b = *(const f32x4_t*)(w + i * 8 + 4);
        bf16x8_t h;
#pragma unroll
        for (int j = 0; j < 4; ++j) {
            h[j]     = (__bf16)a[j];
            h[4 + j] = (__bf16)b[j];
        }
        *(bf16x8_t*)(wbf + i * 8) = h;
    }
}

__device__ __forceinline__ void gload16(const void* g, uint8_t* l) {
    __builtin_amdgcn_global_load_lds(
        (const __attribute__((address_space(1))) uint32_t*)g,
        (__attribute__((address_space(3))) uint32_t*)l, 16, 0, 0);
}

__global__ __launch_bounds__(1024, 2) void moe_gemm(
    const float* __restrict__ inp,
    const __bf16* __restrict__ wbf,
    const float* __restrict__ bias,
    const int* __restrict__ ws,
    float* __restrict__ out)
{
    __shared__ __align__(16) uint8_t smem[LDS_BYTES];

    // ---- balanced bijective XCD mapping (m204): XCD x gets q+(x<r)
    // contiguous real tiles; tail slack spread evenly (was: all on XCD 7) ----
    const int bid  = blockIdx.x;
    const int xcd  = bid & (NXCD - 1);
    const int slot = bid >> 3;                 // 0..143
    const int lt   = slot >> 1;                // local tile idx on this XCD
    const int n0   = (slot & 1) * BN;

    const int ntiles = ws[0];
    const int q = ntiles >> 3, r = ntiles & 7;
    const int cnt_x = q + (xcd < r ? 1 : 0);
    if (lt >= cnt_x) return;
    const int tile = (xcd < r ? xcd * (q + 1) : r * (q + 1) + (xcd - r) * q) + lt;

    const int4 ti = ((const int4*)(ws + 4))[tile];
    const int e = ti.x, row0 = ti.y, row_end = ti.z;

    const int tid  = threadIdx.x;
    const int lane = tid & 63;
    const int wave = tid >> 6;         // 0..15
    const int dr = lane >> 3;          // row-in-8-group (DMA dest)
    const int ac = lane & 7;           // dest 16B chunk (linear)
    const int u  = ac ^ dr;            // logical chunk (group base % 8 == 0)

    // ---- A staging: 2 gload16/wave per K-tile (fp32, R7-proven preswizzle).
    // wave covers rows [wave*16, +16): gload16 i = 8 rows x 128B linear. ----
    const float* asrc[2];
#pragma unroll
    for (int i = 0; i < 2; ++i) {
        int arow = wave * 16 + i * 8 + dr;
        int grow = row0 + arow;
        if (grow > row_end - 1) grow = row_end - 1;   // clamp (C-stores guarded)
        asrc[i] = inp + (size_t)grow * DIN + u * 4;
    }
    // ---- B staging: 1 gload16/wave per K-tile (R12-proven paired layout).
    // LDS row lr (0..127), logical chunk u: u<4 -> dout n0+lr (k-part u&3);
    // u>=4 -> dout n0+lr+128. ----
    const int blr = wave * 8 + dr;
    const __bf16* bsrc = wbf + (size_t)(e * DOUT + n0 + blr + ((u >> 2) << 7)) * DIN
                         + (u & 3) * 8;

    auto issueSet = [&](int tk) {
        const int s = tk % 3;
        uint8_t* adst = smem + ABUF(s) + wave * 2048;
        gload16(asrc[0] + tk * BK, adst);
        gload16(asrc[1] + tk * BK, adst + 1024);
        gload16(bsrc + tk * BK, smem + BBUF(s) + wave * 1024);
    };

    // ---- compute: wave owns 64 rows x 64 cols (4 m x 4 n frags) ----
    const int wr = (wave >> 2) * 64;   // 4 M-bands
    const int wc = (wave & 3) * 64;    // 4 N-bands
    const int frow = lane & 15;
    const int kg   = lane >> 4;

    f32x4_t acc[4][4] = {};

    auto computeTile = [&](int tk) {
        const int s = tk % 3;
        bf16x8_t bg[4];
#pragma unroll
        for (int n = 0; n < 4; ++n) {
            const int row = wc + n * 16 + frow;     // dout-row in tile (0..255)
            const int lr  = row & 127;
            const int h   = row >> 7;
            bg[n] = *(const bf16x8_t*)(smem + BBUF(s) + lr * 128 +
                        ((h * 64 + kg * 16) ^ ((lr & 7) << 4)));
        }
#pragma unroll
        for (int q2 = 0; q2 < 4; ++q2) {
            const int row = wr + q2 * 16 + frow;    // A-row in tile (0..255)
            const uint8_t* pa = smem + ABUF(s) + row * 128;
            const int sw = (row & 7) << 4;
            f32x4_t q0 = *(const f32x4_t*)(pa + ((kg * 32)      ^ sw));
            f32x4_t q1 = *(const f32x4_t*)(pa + ((kg * 32 + 16) ^ sw));
            bf16x8_t af;
#pragma unroll
            for (int j = 0; j < 4; ++j) {
                af[j]     = (__bf16)q0[j];
                af[4 + j] = (__bf16)q1[j];
            }
#pragma unroll
            for (int n = 0; n < 4; ++n)
                acc[q2][n] = __builtin_amdgcn_mfma_f32_16x16x32_bf16(
                    af, bg[n], acc[q2][n], 0, 0, 0);
        }
    };

    // ---- prologue: sets 0,1 in flight; certify set 0 (counted) ----
    issueSet(0); SB();
    issueSet(1); SB();
    WAITV(3); SB();                    // set0 drained by every wave; set1 flies
    BAR();

    // ---- main: 16 K-tiles, ONE barrier each, ring-3 counted flight.
    // Tile t: issue set(t+2) -> slot (t+2)%3 (its readers finished before
    // BAR(t-1)); read+compute slot t%3; WAITV(3) certifies set(t+1) (issued
    // 2 tiles ago) while set(t+2)'s 3 DMAs stay airborne; BAR publishes. ----
#pragma unroll
    for (int t = 0; t < NKT; ++t) {
        if (t + 2 < NKT) { issueSet(t + 2); SB(); }
        computeTile(t);
        if (t + 1 < NKT) {
            if (t + 2 < NKT) { WAITV(3); } else { WAITV(0); }
            SB();
            BAR();
        }
    }

    // ---- epilogue: C/D layout col = lane&15, row = (lane>>4)*4 + j [m89] ----
    const int crow = kg * 4;
    const int ccol = frow;
    float bv[4];
#pragma unroll
    for (int n = 0; n < 4; ++n)
        bv[n] = bias[e * DOUT + n0 + wc + n * 16 + ccol];
#pragma unroll
    for (int m = 0; m < 4; ++m) {
#pragma unroll
        for (int j = 0; j < 4; ++j) {
            const int grow = row0 + wr + m * 16 + crow + j;
            if (grow < row_end) {
                float* orow = out + (size_t)grow * DOUT + n0 + wc + ccol;
#pragma unroll
                for (int n = 0; n < 4; ++n)
                    orow[n * 16] = acc[m][n][j] + bv[n];
            }
        }
    }
}

extern "C" void kernel_launch(void* const* d_in, const int* in_sizes, int n_in,
                              void* d_out, int out_size, void* d_ws, size_t ws_size,
                              hipStream_t stream) {
    const float* inp    = (const float*)d_in[0];
    const float* weight = (const float*)d_in[1];
    const float* bias   = (const float*)d_in[2];
    const int* cnt      = (const int*)d_in[3];   // int64 in reference, delivered as int32
    float* out = (float*)d_out;
    int* ws = (int*)d_ws;
    __bf16* wbf = (__bf16*)((char*)d_ws + WBF_OFF);

    hipLaunchKernelGGL(setup_tiles, dim3(1), dim3(64), 0, stream, cnt, ws);
    hipLaunchKernelGGL(wcvt, dim3(2048), dim3(256), 0, stream, weight, wbf);
    hipLaunchKernelGGL(moe_gemm, dim3(TILES_TOTAL * 2), dim3(1024), 0, stream,
                       inp, wbf, bias, ws, out);
}

// Round 23
// 183.834 us; speedup vs baseline: 1.1047x; 1.1047x over previous
//
#include <hip/hip_runtime.h>
#include <hip/hip_bf16.h>
#include <stdint.h>

#define NE    64
#define DIN   512
#define DOUT  512
#define TTOK  131072
#define BM    256
#define BN    256
#define BK    32
#define NKT   (DIN / BK)              // 16 K-tiles
#define TILES_TOTAL (TTOK / BM + NE)  // 576
#define NXCD  8
#define TPX   (TILES_TOTAL / NXCD)    // 72

typedef __bf16 bf16x8_t __attribute__((ext_vector_type(8)));
typedef float  f32x4_t  __attribute__((ext_vector_type(4)));

// LDS 144 KB, ring-of-3 on BOTH operands (1 block/CU is register-forced:
// 64 AGPR acc + ~46 arch; 1024 thr):
//   A ring: 3 x 32 KB (256 rows x 128B fp32 = 32 k; preswizzled src, (row&7))
//   B ring: 3 x 16 KB (128 LDS rows x 128B bf16; row lr = dout {lr, lr+128},
//           32 k each — R12-proven paired layout, conflict-free)
// Visibility rule (R19): each wave drains its OWN t+1 DMAs (counted WAITV(3))
// BEFORE the single barrier; consumers read after it.
#define ABUF(i) ((i) * 32768)
#define BBUF(i) (98304 + (i) * 16384)
#define LDS_BYTES 147456

#define WAITV(n) asm volatile("s_waitcnt vmcnt(" #n ")" ::: "memory")
#define LGKM0()  asm volatile("s_waitcnt lgkmcnt(0)" ::: "memory")
#define SB() __builtin_amdgcn_sched_barrier(0)
#define BAR() __builtin_amdgcn_s_barrier()

// ws layout: ws[0] = ntiles; tile table (int4) at ws+4; bf16 weight at +32KB
#define WBF_OFF 32768

__global__ void setup_tiles(const int* __restrict__ cnt, int* __restrict__ ws) {
    int e = threadIdx.x;
    if (e >= NE) return;
    int off = 0, tbase = 0;
    for (int i = 0; i < e; ++i) {
        int c = cnt[i];
        off += c;
        tbase += (c + (BM - 1)) / BM;
    }
    int c = cnt[e];
    int nt = (c + (BM - 1)) / BM;
    int* tbl = ws + 4;
    for (int t = 0; t < nt; ++t) {
        int idx = tbase + t;
        tbl[4 * idx + 0] = e;
        tbl[4 * idx + 1] = off + t * BM;
        tbl[4 * idx + 2] = off + c;
        tbl[4 * idx + 3] = 0;
    }
    if (e == NE - 1) ws[0] = tbase + nt;
}

// weight fp32 -> bf16, streaming
__global__ __launch_bounds__(256) void wcvt(const float* __restrict__ w,
                                            __bf16* __restrict__ wbf) {
    const size_t stride = (size_t)gridDim.x * 256;
    size_t i = (size_t)blockIdx.x * 256 + threadIdx.x;
    const size_t n8 = (size_t)NE * DOUT * DIN / 8;
    for (; i < n8; i += stride) {
        f32x4_t a = *(const f32x4_t*)(w + i * 8);
        f32x4_t b = *(const f32x4_t*)(w + i * 8 + 4);
        bf16x8_t h;
#pragma unroll
        for (int j = 0; j < 4; ++j) {
            h[j]     = (__bf16)a[j];
            h[4 + j] = (__bf16)b[j];
        }
        *(bf16x8_t*)(wbf + i * 8) = h;
    }
}

__device__ __forceinline__ void gload16(const void* g, uint8_t* l) {
    __builtin_amdgcn_global_load_lds(
        (const __attribute__((address_space(1))) uint32_t*)g,
        (__attribute__((address_space(3))) uint32_t*)l, 16, 0, 0);
}

__global__ __launch_bounds__(1024, 2) void moe_gemm(
    const float* __restrict__ inp,
    const __bf16* __restrict__ wbf,
    const float* __restrict__ bias,
    const int* __restrict__ ws,
    float* __restrict__ out)
{
    __shared__ __align__(16) uint8_t smem[LDS_BYTES];

    const int bid  = blockIdx.x;
    const int xcd  = bid & (NXCD - 1);
    const int slot = bid >> 3;                 // 0..143
    const int tile = xcd * TPX + (slot >> 1);
    const int n0   = (slot & 1) * BN;

    const int ntiles = ws[0];
    if (tile >= ntiles) return;
    const int4 ti = ((const int4*)(ws + 4))[tile];
    const int e = ti.x, row0 = ti.y, row_end = ti.z;

    const int tid  = threadIdx.x;
    const int lane = tid & 63;
    const int wave = tid >> 6;         // 0..15
    const int dr = lane >> 3;          // row-in-8-group (DMA dest)
    const int ac = lane & 7;           // dest 16B chunk (linear)
    const int u  = ac ^ dr;            // logical chunk (group base % 8 == 0)

    // ---- A staging: 2 gload16/wave per K-tile (fp32, R7-proven preswizzle).
    // wave covers rows [wave*16, +16): gload16 i = 8 rows x 128B linear. ----
    const float* asrc[2];
#pragma unroll
    for (int i = 0; i < 2; ++i) {
        int arow = wave * 16 + i * 8 + dr;
        int grow = row0 + arow;
        if (grow > row_end - 1) grow = row_end - 1;   // clamp (C-stores guarded)
        asrc[i] = inp + (size_t)grow * DIN + u * 4;
    }
    // ---- B staging: 1 gload16/wave per K-tile (R12-proven paired layout).
    // LDS row lr (0..127), logical chunk u: u<4 -> dout n0+lr (k-part u&3);
    // u>=4 -> dout n0+lr+128. ----
    const int blr = wave * 8 + dr;
    const __bf16* bsrc = wbf + (size_t)(e * DOUT + n0 + blr + ((u >> 2) << 7)) * DIN
                         + (u & 3) * 8;

    auto issueSet = [&](int tk) {
        const int s = tk % 3;
        uint8_t* adst = smem + ABUF(s) + wave * 2048;
        gload16(asrc[0] + tk * BK, adst);
        gload16(asrc[1] + tk * BK, adst + 1024);
        gload16(bsrc + tk * BK, smem + BBUF(s) + wave * 1024);
    };

    // ---- compute: wave owns 64 rows x 64 cols (4 m x 4 n frags) ----
    const int wr = (wave >> 2) * 64;   // 4 M-bands
    const int wc = (wave & 3) * 64;    // 4 N-bands
    const int frow = lane & 15;
    const int kg   = lane >> 4;

    f32x4_t acc[4][4] = {};

    auto computeTile = [&](int tk) {
        const int s = tk % 3;
        bf16x8_t bg[4];
#pragma unroll
        for (int n = 0; n < 4; ++n) {
            const int row = wc + n * 16 + frow;     // dout-row in tile (0..255)
            const int lr  = row & 127;
            const int h   = row >> 7;
            bg[n] = *(const bf16x8_t*)(smem + BBUF(s) + lr * 128 +
                        ((h * 64 + kg * 16) ^ ((lr & 7) << 4)));
        }
#pragma unroll
        for (int q = 0; q < 4; ++q) {
            const int row = wr + q * 16 + frow;     // A-row in tile (0..255)
            const uint8_t* pa = smem + ABUF(s) + row * 128;
            const int sw = (row & 7) << 4;
            f32x4_t q0 = *(const f32x4_t*)(pa + ((kg * 32)      ^ sw));
            f32x4_t q1 = *(const f32x4_t*)(pa + ((kg * 32 + 16) ^ sw));
            bf16x8_t af;
#pragma unroll
            for (int j = 0; j < 4; ++j) {
                af[j]     = (__bf16)q0[j];
                af[4 + j] = (__bf16)q1[j];
            }
            __builtin_amdgcn_s_setprio(1);
#pragma unroll
            for (int n = 0; n < 4; ++n)
                acc[q][n] = __builtin_amdgcn_mfma_f32_16x16x32_bf16(
                    af, bg[n], acc[q][n], 0, 0, 0);
            __builtin_amdgcn_s_setprio(0);
        }
    };

    // ---- prologue: sets 0,1 in flight; certify set 0 (counted) ----
    issueSet(0); SB();
    issueSet(1); SB();
    WAITV(3); SB();                    // set0 drained by every wave; set1 flies
    BAR();

    // ---- main: 16 K-tiles, ONE barrier each, ring-3 counted flight.
    // Tile t: issue set(t+2) -> slot (t+2)%3 (its readers finished before
    // BAR(t-1)); read+compute slot t%3; WAITV(3) certifies set(t+1) (issued
    // 2 tiles ago, ~1.7-tile flight) while set(t+2)'s 3 DMAs stay airborne;
    // BAR publishes set(t+1) to all waves. ----
#pragma unroll
    for (int t = 0; t < NKT; ++t) {
        if (t + 2 < NKT) { issueSet(t + 2); SB(); }
        computeTile(t);
        if (t + 1 < NKT) {
            if (t + 2 < NKT) { WAITV(3); } else { WAITV(0); }
            SB();
            BAR();
        }
    }

    // ---- epilogue: C/D layout col = lane&15, row = (lane>>4)*4 + j [m89] ----
    const int crow = kg * 4;
    const int ccol = frow;
    float bv[4];
#pragma unroll
    for (int n = 0; n < 4; ++n)
        bv[n] = bias[e * DOUT + n0 + wc + n * 16 + ccol];
#pragma unroll
    for (int m = 0; m < 4; ++m) {
#pragma unroll
        for (int j = 0; j < 4; ++j) {
            const int grow = row0 + wr + m * 16 + crow + j;
            if (grow < row_end) {
                float* orow = out + (size_t)grow * DOUT + n0 + wc + ccol;
#pragma unroll
                for (int n = 0; n < 4; ++n)
                    orow[n * 16] = acc[m][n][j] + bv[n];
            }
        }
    }
}

extern "C" void kernel_launch(void* const* d_in, const int* in_sizes, int n_in,
                              void* d_out, int out_size, void* d_ws, size_t ws_size,
                              hipStream_t stream) {
    const float* inp    = (const float*)d_in[0];
    const float* weight = (const float*)d_in[1];
    const float* bias   = (const float*)d_in[2];
    const int* cnt      = (const int*)d_in[3];   // int64 in reference, delivered as int32
    float* out = (float*)d_out;
    int* ws = (int*)d_ws;
    __bf16* wbf = (__bf16*)((char*)d_ws + WBF_OFF);

    hipLaunchKernelGGL(setup_tiles, dim3(1), dim3(64), 0, stream, cnt, ws);
    hipLaunchKernelGGL(wcvt, dim3(2048), dim3(256), 0, stream, weight, wbf);
    hipLaunchKernelGGL(moe_gemm, dim3(TILES_TOTAL * 2), dim3(1024), 0, stream,
                       inp, wbf, bias, ws, out);
}

// Round 24
// 183.115 us; speedup vs baseline: 1.1090x; 1.0039x over previous
//
#include <hip/hip_runtime.h>
#include <hip/hip_bf16.h>
#include <stdint.h>

#define NE    64
#define DIN   512
#define DOUT  512
#define TTOK  131072
#define BM    256
#define BN    256
#define BK    32
#define NKT   (DIN / BK)              // 16 K-tiles
#define TILES_TOTAL (TTOK / BM + NE)  // 576 (grid bound)
#define NXCD  8

typedef __bf16 bf16x8_t __attribute__((ext_vector_type(8)));
typedef float  f32x4_t  __attribute__((ext_vector_type(4)));

// LDS 144 KB, ring-of-3 on BOTH operands (1 block/CU is register-forced:
// 64 AGPR acc + ~46 arch; 1024 thr):
//   A ring: 3 x 32 KB (256 rows x 128B fp32 = 32 k; preswizzled src, (row&7))
//   B ring: 3 x 16 KB (128 LDS rows x 128B bf16; row lr = dout {lr, lr+128},
//           32 k each — R12-proven paired layout, conflict-free)
// Visibility rule (R19): each wave drains its OWN t+1 DMAs (counted WAITV(3))
// BEFORE the single barrier; consumers read after it.
#define ABUF(i) ((i) * 32768)
#define BBUF(i) (98304 + (i) * 16384)
#define LDS_BYTES 147456

#define WAITV(n) asm volatile("s_waitcnt vmcnt(" #n ")" ::: "memory")
#define SB() __builtin_amdgcn_sched_barrier(0)
#define BAR() __builtin_amdgcn_s_barrier()

// ws layout: ws[0] = ntiles; tile table (int4) at ws+4; bf16 weight at +32KB
#define WBF_OFF 32768

__global__ void setup_tiles(const int* __restrict__ cnt, int* __restrict__ ws) {
    int e = threadIdx.x;
    if (e >= NE) return;
    int off = 0, tbase = 0;
    for (int i = 0; i < e; ++i) {
        int c = cnt[i];
        off += c;
        tbase += (c + (BM - 1)) / BM;
    }
    int c = cnt[e];
    int nt = (c + (BM - 1)) / BM;
    int* tbl = ws + 4;
    for (int t = 0; t < nt; ++t) {
        int idx = tbase + t;
        tbl[4 * idx + 0] = e;
        tbl[4 * idx + 1] = off + t * BM;
        tbl[4 * idx + 2] = off + c;
        tbl[4 * idx + 3] = 0;
    }
    if (e == NE - 1) ws[0] = tbase + nt;
}

// weight fp32 -> bf16, streaming
__global__ __launch_bounds__(256) void wcvt(const float* __restrict__ w,
                                            __bf16* __restrict__ wbf) {
    const size_t stride = (size_t)gridDim.x * 256;
    size_t i = (size_t)blockIdx.x * 256 + threadIdx.x;
    const size_t n8 = (size_t)NE * DOUT * DIN / 8;
    for (; i < n8; i += stride) {
        f32x4_t a = *(const f32x4_t*)(w + i * 8);
        f32x4_t b = *(const f32x4_t*)(w + i * 8 + 4);
        bf16x8_t h;
#pragma unroll
        for (int j = 0; j < 4; ++j) {
            h[j]     = (__bf16)a[j];
            h[4 + j] = (__bf16)b[j];
        }
        *(bf16x8_t*)(wbf + i * 8) = h;
    }
}

__device__ __forceinline__ void gload16(const void* g, uint8_t* l) {
    __builtin_amdgcn_global_load_lds(
        (const __attribute__((address_space(1))) uint32_t*)g,
        (__attribute__((address_space(3))) uint32_t*)l, 16, 0, 0);
}

__global__ __launch_bounds__(1024, 2) void moe_gemm(
    const float* __restrict__ inp,
    const __bf16* __restrict__ wbf,
    const float* __restrict__ bias,
    const int* __restrict__ ws,
    float* __restrict__ out)
{
    __shared__ __align__(16) uint8_t smem[LDS_BYTES];

    // ---- balanced bijective XCD mapping (m204): XCD x gets q+(x<r)
    // contiguous real tiles — tail slack spread within 1 tile per XCD
    // (static TPX map put ALL slack on XCD 7: ~6% chip idle tail).
    // Preamble-only change vs R23; loop body byte-identical (setprio kept). ----
    const int bid  = blockIdx.x;
    const int xcd  = bid & (NXCD - 1);
    const int slot = bid >> 3;                 // 0..143
    const int lt   = slot >> 1;                // local tile idx on this XCD
    const int n0   = (slot & 1) * BN;

    const int ntiles = ws[0];
    const int qx = ntiles >> 3, rx = ntiles & 7;
    const int cnt_x = qx + (xcd < rx ? 1 : 0);
    if (lt >= cnt_x) return;
    const int tile = (xcd < rx ? xcd * (qx + 1)
                               : rx * (qx + 1) + (xcd - rx) * qx) + lt;

    const int4 ti = ((const int4*)(ws + 4))[tile];
    const int e = ti.x, row0 = ti.y, row_end = ti.z;

    const int tid  = threadIdx.x;
    const int lane = tid & 63;
    const int wave = tid >> 6;         // 0..15
    const int dr = lane >> 3;          // row-in-8-group (DMA dest)
    const int ac = lane & 7;           // dest 16B chunk (linear)
    const int u  = ac ^ dr;            // logical chunk (group base % 8 == 0)

    // ---- A staging: 2 gload16/wave per K-tile (fp32, R7-proven preswizzle).
    // wave covers rows [wave*16, +16): gload16 i = 8 rows x 128B linear. ----
    const float* asrc[2];
#pragma unroll
    for (int i = 0; i < 2; ++i) {
        int arow = wave * 16 + i * 8 + dr;
        int grow = row0 + arow;
        if (grow > row_end - 1) grow = row_end - 1;   // clamp (C-stores guarded)
        asrc[i] = inp + (size_t)grow * DIN + u * 4;
    }
    // ---- B staging: 1 gload16/wave per K-tile (R12-proven paired layout).
    // LDS row lr (0..127), logical chunk u: u<4 -> dout n0+lr (k-part u&3);
    // u>=4 -> dout n0+lr+128. ----
    const int blr = wave * 8 + dr;
    const __bf16* bsrc = wbf + (size_t)(e * DOUT + n0 + blr + ((u >> 2) << 7)) * DIN
                         + (u & 3) * 8;

    auto issueSet = [&](int tk) {
        const int s = tk % 3;
        uint8_t* adst = smem + ABUF(s) + wave * 2048;
        gload16(asrc[0] + tk * BK, adst);
        gload16(asrc[1] + tk * BK, adst + 1024);
        gload16(bsrc + tk * BK, smem + BBUF(s) + wave * 1024);
    };

    // ---- compute: wave owns 64 rows x 64 cols (4 m x 4 n frags) ----
    const int wr = (wave >> 2) * 64;   // 4 M-bands
    const int wc = (wave & 3) * 64;    // 4 N-bands
    const int frow = lane & 15;
    const int kg   = lane >> 4;

    f32x4_t acc[4][4] = {};

    auto computeTile = [&](int tk) {
        const int s = tk % 3;
        bf16x8_t bg[4];
#pragma unroll
        for (int n = 0; n < 4; ++n) {
            const int row = wc + n * 16 + frow;     // dout-row in tile (0..255)
            const int lr  = row & 127;
            const int h   = row >> 7;
            bg[n] = *(const bf16x8_t*)(smem + BBUF(s) + lr * 128 +
                        ((h * 64 + kg * 16) ^ ((lr & 7) << 4)));
        }
#pragma unroll
        for (int q = 0; q < 4; ++q) {
            const int row = wr + q * 16 + frow;     // A-row in tile (0..255)
            const uint8_t* pa = smem + ABUF(s) + row * 128;
            const int sw = (row & 7) << 4;
            f32x4_t q0 = *(const f32x4_t*)(pa + ((kg * 32)      ^ sw));
            f32x4_t q1 = *(const f32x4_t*)(pa + ((kg * 32 + 16) ^ sw));
            bf16x8_t af;
#pragma unroll
            for (int j = 0; j < 4; ++j) {
                af[j]     = (__bf16)q0[j];
                af[4 + j] = (__bf16)q1[j];
            }
            __builtin_amdgcn_s_setprio(1);
#pragma unroll
            for (int n = 0; n < 4; ++n)
                acc[q][n] = __builtin_amdgcn_mfma_f32_16x16x32_bf16(
                    af, bg[n], acc[q][n], 0, 0, 0);
            __builtin_amdgcn_s_setprio(0);
        }
    };

    // ---- prologue: sets 0,1 in flight; certify set 0 (counted) ----
    issueSet(0); SB();
    issueSet(1); SB();
    WAITV(3); SB();                    // set0 drained by every wave; set1 flies
    BAR();

    // ---- main: 16 K-tiles, ONE barrier each, ring-3 counted flight.
    // Tile t: issue set(t+2) -> slot (t+2)%3 (its readers finished before
    // BAR(t-1)); read+compute slot t%3; WAITV(3) certifies set(t+1) (issued
    // 2 tiles ago, ~1.7-tile flight) while set(t+2)'s 3 DMAs stay airborne;
    // BAR publishes set(t+1) to all waves. ----
#pragma unroll
    for (int t = 0; t < NKT; ++t) {
        if (t + 2 < NKT) { issueSet(t + 2); SB(); }
        computeTile(t);
        if (t + 1 < NKT) {
            if (t + 2 < NKT) { WAITV(3); } else { WAITV(0); }
            SB();
            BAR();
        }
    }

    // ---- epilogue: C/D layout col = lane&15, row = (lane>>4)*4 + j [m89] ----
    const int crow = kg * 4;
    const int ccol = frow;
    float bv[4];
#pragma unroll
    for (int n = 0; n < 4; ++n)
        bv[n] = bias[e * DOUT + n0 + wc + n * 16 + ccol];
#pragma unroll
    for (int m = 0; m < 4; ++m) {
#pragma unroll
        for (int j = 0; j < 4; ++j) {
            const int grow = row0 + wr + m * 16 + crow + j;
            if (grow < row_end) {
                float* orow = out + (size_t)grow * DOUT + n0 + wc + ccol;
#pragma unroll
                for (int n = 0; n < 4; ++n)
                    orow[n * 16] = acc[m][n][j] + bv[n];
            }
        }
    }
}

extern "C" void kernel_launch(void* const* d_in, const int* in_sizes, int n_in,
                              void* d_out, int out_size, void* d_ws, size_t ws_size,
                              hipStream_t stream) {
    const float* inp    = (const float*)d_in[0];
    const float* weight = (const float*)d_in[1];
    const float* bias   = (const float*)d_in[2];
    const int* cnt      = (const int*)d_in[3];   // int64 in reference, delivered as int32
    float* out = (float*)d_out;
    int* ws = (int*)d_ws;
    __bf16* wbf = (__bf16*)((char*)d_ws + WBF_OFF);

    hipLaunchKernelGGL(setup_tiles, dim3(1), dim3(64), 0, stream, cnt, ws);
    hipLaunchKernelGGL(wcvt, dim3(2048), dim3(256), 0, stream, weight, wbf);
    hipLaunchKernelGGL(moe_gemm, dim3(TILES_TOTAL * 2), dim3(1024), 0, stream,
                       inp, wbf, bias, ws, out);
}